// Round 13
// baseline (3251.624 us; speedup 1.0000x reference)
//
#include <hip/hip_runtime.h>
#include <stdint.h>

#define BATCH 8
#define C 128
#define TPB 512
#define TILE_R 512
#define KCH 16
#define NCH (C / KCH)     // 8
#define SROWP 640         // padded k-row capacity: p(r)=r+((r>>4)<<2), max 635
#define HGRID 2048

// order-preserving float -> uint key (monotone: a<b  <=>  key(a)<key(b))
__device__ __forceinline__ unsigned f2key(float f){
  unsigned b = __float_as_uint(f);
  return (b & 0x80000000u) ? ~b : (b | 0x80000000u);
}

// ---------------------------------------------------------------------------
// Outer-product GEMM, 16x8 per-thread tile (was 8x8 for r5-r11).
// WHY: r5-r11 all plateaued at 443-470us / VALU 45-48% because the 8x8 tile
// is LDS-BW-bound: 4 b128 reads per 64 FMAs -> 76 TB/s required at the FMA
// floor > 69 TB/s LDS peak. 16x8 needs 6 b128 per 128 FMAs -> 57 TB/s.
// (r12's packed-FMA was a dead end: scalar v_fma_f32 already issues 32/cyc/
// SIMD = 157 TF; packing only added movs and VGPR pressure.)
// Geometry: 8 waves (4 row-groups x 2 col-groups), wave tile 128x64, block
// tile 512x128, grid = 1563 one-tile blocks (512 !| 800000 -> tail guards).
// A staged in [2][16][SROWP] LDS, 16-k chunks (64B/row/stage, coalesced),
// rows PADDED +4 floats per 16 (p(r)=r+((r>>4)<<2)) so the 8 lane-groups'
// b128 A-reads (20-float spacing) cover all 32 banks conflict-free
// (unpadded 16-spacing = 4-way conflict = 1.58x). W1 in LDS [k][c] (2-way
// aliasing = free). LDS 144KB -> 1 block/CU, 2 waves/SIMD (enough: we are
// throughput-bound, not latency-bound).
// FMA chains (h and pred) operand/order-identical to rounds 1-11.
// ---------------------------------------------------------------------------
__global__ __launch_bounds__(TPB, 1) void k_gemm(
    const float* __restrict__ fea, const float* __restrict__ W1,
    const float* __restrict__ b1, const float* __restrict__ W2,
    const float* __restrict__ b2, const int* __restrict__ vox,
    float* __restrict__ out, float* __restrict__ pred,
    unsigned* __restrict__ segkey, int N)
{
  __shared__ float sW1[C * C];            // 64KB, natural [k][c]
  __shared__ float sA[2][KCH][SROWP];     // 80KB, padded transposed fea tile

  const int tid  = threadIdx.x;
  const int lane = tid & 63;
  const int wid  = tid >> 6;              // 0..7
  const int wr   = wid >> 1;              // 0..3 row-group (128 rows each)
  const int wc   = wid & 1;               // 0..1 col-group
  const int rowoff = wr * 128 + (lane >> 3) * 16;   // 0..496 (16-aligned)
  const int prow   = rowoff + ((rowoff >> 4) << 2); // padded base = 20*(rowoff/16)
  const int coloff = wc * 64 + (lane & 7) * 8;      // 0..120

  { // stage W1 once
    const float4* src = (const float4*)W1;
    float4* dst = (float4*)sW1;
    #pragma unroll
    for (int i = 0; i < (C * C / 4) / TPB; ++i)
      dst[i * TPB + tid] = src[i * TPB + tid];
  }
  float b1v[8];
  #pragma unroll
  for (int i = 0; i < 8; ++i) b1v[i] = b1[coloff + i];
  const double b2d = (double)b2[0];

  const size_t trow = (size_t)blockIdx.x * TILE_R;
  const int srow  = tid;                              // staging row 0..511
  const int psrow = srow + ((srow >> 4) << 2);        // padded staging row
  const bool svalid = (trow + srow) < (size_t)N;
  const float* frow = fea + (trow + srow) * C;

  // ---- prologue: stage chunk 0 (64B contiguous per row, coalesced) ----
  float4 st[4] = {};
  if (svalid) {
    #pragma unroll
    for (int q = 0; q < 4; ++q) st[q] = *(const float4*)(frow + q * 4);
  }
  {
    float* d = &sA[0][0][psrow];
    #pragma unroll
    for (int q = 0; q < 4; ++q) {
      d[(q*4+0)*SROWP] = st[q].x; d[(q*4+1)*SROWP] = st[q].y;
      d[(q*4+2)*SROWP] = st[q].z; d[(q*4+3)*SROWP] = st[q].w;
    }
  }
  __syncthreads();

  float acc[16][8];
  #pragma unroll
  for (int j = 0; j < 16; ++j)
    #pragma unroll
    for (int i = 0; i < 8; ++i) acc[j][i] = b1v[i];

  // ---- k-chunk loop: one barrier per 16-k chunk ----
  #pragma unroll 1
  for (int kb = 0; kb < NCH; ++kb) {
    if (kb + 1 < NCH && svalid) {   // prefetch next chunk (64B contiguous)
      #pragma unroll
      for (int q = 0; q < 4; ++q)
        st[q] = *(const float4*)(frow + (kb + 1) * KCH + q * 4);
    }
    const float* sAc = &sA[kb & 1][0][0];
    const float* sWb = &sW1[kb * KCH * C];
    #pragma unroll
    for (int k = 0; k < KCH; ++k) {
      float4 a0 = *(const float4*)(sAc + k * SROWP + prow);
      float4 a1 = *(const float4*)(sAc + k * SROWP + prow + 4);
      float4 a2 = *(const float4*)(sAc + k * SROWP + prow + 8);
      float4 a3 = *(const float4*)(sAc + k * SROWP + prow + 12);
      float4 bA = *(const float4*)(sWb + k * C + coloff);
      float4 bB = *(const float4*)(sWb + k * C + coloff + 4);
      float af[16] = {a0.x, a0.y, a0.z, a0.w, a1.x, a1.y, a1.z, a1.w,
                      a2.x, a2.y, a2.z, a2.w, a3.x, a3.y, a3.z, a3.w};
      float bf[8]  = {bA.x, bA.y, bA.z, bA.w, bB.x, bB.y, bB.z, bB.w};
      #pragma unroll
      for (int j = 0; j < 16; ++j)
        #pragma unroll
        for (int i = 0; i < 8; ++i)
          acc[j][i] = fmaf(af[j], bf[i], acc[j][i]);
    }
    if (kb + 1 < NCH) {
      float* d = &sA[(kb + 1) & 1][0][psrow];
      #pragma unroll
      for (int q = 0; q < 4; ++q) {
        d[(q*4+0)*SROWP] = st[q].x; d[(q*4+1)*SROWP] = st[q].y;
        d[(q*4+2)*SROWP] = st[q].z; d[(q*4+3)*SROWP] = st[q].w;
      }
    }
    __syncthreads();
  }

  // ---- epilogue: relu + store h, f64 pred, segment max ----
  float w2f[8];
  #pragma unroll
  for (int i = 0; i < 8; ++i) w2f[i] = W2[coloff + i];
  double pdv[16];
  #pragma unroll
  for (int j = 0; j < 16; ++j) {
    float hv[8];
    #pragma unroll
    for (int i = 0; i < 8; ++i) hv[i] = fmaxf(acc[j][i], 0.f);
    const size_t row = trow + rowoff + j;
    if (row < (size_t)N) {
      *(float4*)(out + row * C + coloff)     = make_float4(hv[0], hv[1], hv[2], hv[3]);
      *(float4*)(out + row * C + coloff + 4) = make_float4(hv[4], hv[5], hv[6], hv[7]);
    }
    double pd = 0.0;
    #pragma unroll
    for (int i = 0; i < 8; ++i) pd += (double)hv[i] * (double)w2f[i];
    pdv[j] = pd;
  }
  #pragma unroll
  for (int j = 0; j < 16; ++j) {   // reduce over the 8-lane col group
    double pd = pdv[j];
    pd += __shfl_xor(pd, 1, 64);
    pd += __shfl_xor(pd, 2, 64);
    pd += __shfl_xor(pd, 4, 64);
    pdv[j] = pd;
  }
  double* sPred = (double*)&sA[0][0][0];   // 1024 doubles (8KB) overlay
  if ((lane & 7) == 0) {
    #pragma unroll
    for (int j = 0; j < 16; ++j) sPred[wc * TILE_R + rowoff + j] = pdv[j];
  }
  __syncthreads();
  {
    const size_t row = trow + tid;           // tid covers 0..511 == TILE_R
    if (row < (size_t)N) {
      const double s = sPred[tid] + sPred[TILE_R + tid] + b2d;
      const float pv = (float)s;
      pred[row] = pv;
      atomicMax(&segkey[vox[row]], f2key(pv));
    }
  }
}

// ---------------------------------------------------------------------------
// Pass A: valkey + per-row histogram of byte1 (vk>>24), LDS-accumulated.
// ---------------------------------------------------------------------------
__global__ __launch_bounds__(256) void k_histA(
    const float* __restrict__ pred, const int* __restrict__ vox,
    const unsigned* __restrict__ segkey, unsigned* __restrict__ valkey,
    unsigned* __restrict__ histA, int N, int M)
{
  __shared__ unsigned lh[BATCH * 256];
  for (int b = threadIdx.x; b < BATCH * 256; b += 256) lh[b] = 0;
  __syncthreads();
  const int stride = gridDim.x * 256;
  for (int i = blockIdx.x * 256 + threadIdx.x; i < N; i += stride) {
    unsigned kk = f2key(pred[i]);
    unsigned vk = (kk == segkey[vox[i]]) ? 0xFFFFFFFFu : kk;
    valkey[i] = vk;
    atomicAdd(&lh[(i / M) * 256 + (vk >> 24)], 1u);
  }
  __syncthreads();
  for (int b = threadIdx.x; b < BATCH * 256; b += 256)
    if (lh[b]) atomicAdd(&histA[b], lh[b]);
}

// Pass B: byte2 among elements whose byte1 matches the selected bin.
__global__ __launch_bounds__(256) void k_histB(
    const unsigned* __restrict__ valkey, const unsigned* __restrict__ sel,
    unsigned* __restrict__ histB, int N, int M)
{
  __shared__ unsigned lh[BATCH * 256];
  for (int b = threadIdx.x; b < BATCH * 256; b += 256) lh[b] = 0;
  __syncthreads();
  const int stride = gridDim.x * 256;
  for (int i = blockIdx.x * 256 + threadIdx.x; i < N; i += stride) {
    unsigned vk = valkey[i];
    int row = i / M;
    if ((vk >> 24) == sel[row * 4 + 0])
      atomicAdd(&lh[row * 256 + ((vk >> 16) & 255u)], 1u);
  }
  __syncthreads();
  for (int b = threadIdx.x; b < BATCH * 256; b += 256)
    if (lh[b]) atomicAdd(&histB[b], lh[b]);
}

// Pass C: low 16 bits among elements whose top16 matches (few -> global ok).
__global__ __launch_bounds__(256) void k_histC(
    const unsigned* __restrict__ valkey, const unsigned* __restrict__ sel,
    unsigned* __restrict__ histC, int N, int M)
{
  const int stride = gridDim.x * 256;
  for (int i = blockIdx.x * 256 + threadIdx.x; i < N; i += stride) {
    unsigned vk = valkey[i];
    int row = i / M;
    if ((vk >> 16) == sel[row * 4 + 0])
      atomicAdd(&histC[(size_t)row * 65536 + (vk & 0xFFFFu)], 1u);
  }
}

// scans: find smallest bin with cumulative count >= k (k = M - target_num)
__global__ void k_scan256(const unsigned* __restrict__ hist,
                          unsigned* __restrict__ sel,
                          const int* __restrict__ tnum, int M, int pass)
{
  const int row = blockIdx.x;
  __shared__ unsigned h[256];
  h[threadIdx.x] = hist[row * 256 + threadIdx.x];
  __syncthreads();
  if (threadIdx.x == 0) {
    const unsigned k = (unsigned)(M - tnum[0]);
    unsigned cum = (pass == 0) ? 0u : sel[row * 4 + 1];
    unsigned bin = 255;
    for (int i = 0; i < 256; ++i) {
      if (cum + h[i] >= k) { bin = (unsigned)i; break; }
      cum += h[i];
    }
    if (pass == 0) { sel[row * 4 + 0] = bin; }
    else           { sel[row * 4 + 0] = (sel[row * 4 + 0] << 8) | bin; }
    sel[row * 4 + 1] = cum;
  }
}

__global__ void k_scan64k(const unsigned* __restrict__ hist,
                          unsigned* __restrict__ sel,
                          const int* __restrict__ tnum, int M)
{
  const int row = blockIdx.x;
  const int t = threadIdx.x;  // 256
  const unsigned* h = hist + (size_t)row * 65536;
  __shared__ unsigned part[256];
  const uint4* hv = (const uint4*)(h + t * 256);
  unsigned s = 0;
  for (int i = 0; i < 64; ++i) { uint4 v = hv[i]; s += v.x + v.y + v.z + v.w; }
  part[t] = s;
  __syncthreads();
  if (t == 0) {
    const unsigned k = (unsigned)(M - tnum[0]);
    unsigned cum = sel[row * 4 + 1];
    int seg = 255;
    for (int i = 0; i < 256; ++i) {
      if (cum + part[i] >= k) { seg = i; break; }
      cum += part[i];
    }
    unsigned bin = 0;
    for (int i = 0; i < 256; ++i) {
      unsigned c = h[seg * 256 + i];
      if (cum + c >= k) { bin = (unsigned)(seg * 256 + i); break; }
      cum += c;
    }
    sel[row * 4 + 2] = (sel[row * 4 + 0] << 16) | bin;
  }
}

__global__ void k_scatter(const int* __restrict__ tidx, float* __restrict__ kt, int n)
{
  int i = blockIdx.x * blockDim.x + threadIdx.x;
  if (i < n) kt[tidx[i]] = 1.0f;
}

// zero rows that are not kept.  keep = (valkey > thr) | is_target
__global__ __launch_bounds__(256) void k_final(const unsigned* __restrict__ valkey,
    const float* __restrict__ kt, const unsigned* __restrict__ sel,
    float* __restrict__ out, int N, int M)
{
  const int wid = threadIdx.x >> 6;
  const int lane = threadIdx.x & 63;
  const int nw = gridDim.x * 4;
  for (int r = blockIdx.x * 4 + wid; r < N; r += nw) {
    unsigned vk = valkey[r];
    float kv = kt[r];
    unsigned thr = sel[(r / M) * 4 + 2];
    bool keep = (vk > thr) || (kv != 0.0f);
    if (!keep)
      *(float2*)&out[(size_t)r * C + lane * 2] = make_float2(0.f, 0.f);
  }
}

// ---------------------------------------------------------------------------
extern "C" void kernel_launch(void* const* d_in, const int* in_sizes, int n_in,
                              void* d_out, int out_size, void* d_ws, size_t ws_size,
                              hipStream_t stream)
{
  const float* fea = (const float*)d_in[0];
  const float* W1  = (const float*)d_in[1];
  const float* b1  = (const float*)d_in[2];
  const float* W2  = (const float*)d_in[3];
  const float* b2  = (const float*)d_in[4];
  const int* vox   = (const int*)d_in[5];
  const int* tidx  = (const int*)d_in[6];
  const int* tnum  = (const int*)d_in[7];

  const int N = in_sizes[5];      // 800000
  const int M = N / BATCH;        // 100000
  const int nT = in_sizes[6];     // 400000
  const int nTiles = (N + TILE_R - 1) / TILE_R;   // 1563

  float* out  = (float*)d_out;
  float* pred = out + (size_t)N * C;
  float* kt   = pred + N;

  // workspace layout (zeroed region first, then valkey)
  char* w = (char*)d_ws;
  unsigned* segkey = (unsigned*)(w);                       // 512KB
  unsigned* histA  = (unsigned*)(w + (512u << 10));        // 8KB
  unsigned* histB  = (unsigned*)(w + (520u << 10));        // 8KB
  unsigned* sel    = (unsigned*)(w + (528u << 10));        // 4KB
  unsigned* histC  = (unsigned*)(w + (532u << 10));        // 2MB
  unsigned* valkey = (unsigned*)(w + (532u << 10) + (2u << 20));

  const size_t zbytes = (532u << 10) + (2u << 20);
  hipMemsetAsync(d_ws, 0, zbytes, stream);
  hipMemsetAsync(kt, 0, (size_t)N * sizeof(float), stream);

  k_scatter<<<(nT + 255) / 256, 256, 0, stream>>>(tidx, kt, nT);
  k_gemm<<<nTiles, TPB, 0, stream>>>(fea, W1, b1, W2, b2, vox,
                                     out, pred, segkey, N);
  k_histA<<<HGRID, 256, 0, stream>>>(pred, vox, segkey, valkey, histA, N, M);
  k_scan256<<<BATCH, 256, 0, stream>>>(histA, sel, tnum, M, 0);
  k_histB<<<HGRID, 256, 0, stream>>>(valkey, sel, histB, N, M);
  k_scan256<<<BATCH, 256, 0, stream>>>(histB, sel, tnum, M, 1);
  k_histC<<<HGRID, 256, 0, stream>>>(valkey, sel, histC, N, M);
  k_scan64k<<<BATCH, 256, 0, stream>>>(histC, sel, tnum, M);
  k_final<<<2048, 256, 0, stream>>>(valkey, kt, sel, out, N, M);
}

// Round 14
// 1060.095 us; speedup vs baseline: 3.0673x; 3.0673x over previous
//
#include <hip/hip_runtime.h>
#include <stdint.h>

#define BATCH 8
#define C 128
#define TPB 256
#define TILE_R 256
#define KCH 16
#define NCH (C / KCH)     // 8
#define SROWP 320         // padded row capacity: p(r)=r+((r>>4)<<2), max 315
#define HGRID 2048

// order-preserving float -> uint key (monotone: a<b  <=>  key(a)<key(b))
__device__ __forceinline__ unsigned f2key(float f){
  unsigned b = __float_as_uint(f);
  return (b & 0x80000000u) ? ~b : (b | 0x80000000u);
}

// ---------------------------------------------------------------------------
// Outer-product GEMM, 16x8 per-thread tile on 256-THREAD blocks.
// Lesson r13: hipcc hard-caps TPB=512 bodies at 128 VGPR (observed 124-128 in
// r5/7/8/9/13 regardless of launch_bounds) -> the 16x8 tile (needs ~190)
// spilled. TPB=256 allocates freely above 128 (r12: 140, no spill).
// WHY 16x8: r5-r11 plateaued at 443-470us / VALU 45-48% with 4-6 loads per
// 64 FMAs/k; 16x8 feeds 128 FMAs from 6 loads -> halves per-wave stall share.
// Geometry: 4 waves (2 row-groups x 2 col-groups), wave tile 128x64, block
// tile 256x128, grid = 800000/256 = 3125 exact (no tail guards).
// A in LDS [2][16][320] = 40KB, padded so the 8 lane-groups' b128 A-reads
// (20-float spacing) cover all 32 banks exactly once (conflict-free).
// B (W1, 64KB, L2-hot) from global, 2-deep register pipeline over absolute k
// (r12-proven path, scalar FMAs). Expected ~200 VGPR -> 2 waves/SIMD,
// 2 blocks/CU (LDS would allow 4). 8 barriers/tile.
// FMA chains (h and pred) operand/order-identical to rounds 1-13.
// ---------------------------------------------------------------------------
__global__ __launch_bounds__(TPB, 1) void k_gemm(
    const float* __restrict__ fea, const float* __restrict__ W1,
    const float* __restrict__ b1, const float* __restrict__ W2,
    const float* __restrict__ b2, const int* __restrict__ vox,
    float* __restrict__ out, float* __restrict__ pred,
    unsigned* __restrict__ segkey, int N)
{
  __shared__ float sA[2][KCH][SROWP];   // 40KB, padded transposed fea tile

  const int tid  = threadIdx.x;
  const int lane = tid & 63;
  const int wid  = tid >> 6;              // 0..3
  const int wr   = wid >> 1;              // 0..1 row-group (128 rows)
  const int wc   = wid & 1;               // 0..1 col-group (64 cols)
  const int rowoff = wr * 128 + (lane >> 3) * 16;   // 0..240 (16-aligned)
  const int prow   = rowoff + ((rowoff >> 4) << 2); // = 20*(rowoff/16)
  const int coloff = wc * 64 + (lane & 7) * 8;      // 0..120

  float b1v[8];
  #pragma unroll
  for (int i = 0; i < 8; ++i) b1v[i] = b1[coloff + i];
  const double b2d = (double)b2[0];

  const float* wcol = W1 + coloff;        // B(k) = wcol[k*C .. +7]

  const size_t trow = (size_t)blockIdx.x * TILE_R;   // exact: N = 3125*256
  const int ptid = tid + ((tid >> 4) << 2);          // padded staging row
  const float* frow = fea + (trow + tid) * C;

  // ---- prologue: stage chunk 0 (64B contiguous per row, coalesced) ----
  float4 st[4];
  #pragma unroll
  for (int q = 0; q < 4; ++q) st[q] = *(const float4*)(frow + q * 4);
  {
    float* d = &sA[0][0][ptid];
    #pragma unroll
    for (int q = 0; q < 4; ++q) {
      d[(q*4+0)*SROWP] = st[q].x; d[(q*4+1)*SROWP] = st[q].y;
      d[(q*4+2)*SROWP] = st[q].z; d[(q*4+3)*SROWP] = st[q].w;
    }
  }
  // prime B pipeline (k=0,1)
  float4 bAc = *(const float4*)(wcol);
  float4 bBc = *(const float4*)(wcol + 4);
  float4 bAn = *(const float4*)(wcol + C);
  float4 bBn = *(const float4*)(wcol + C + 4);
  __syncthreads();

  float acc[16][8];
  #pragma unroll
  for (int j = 0; j < 16; ++j)
    #pragma unroll
    for (int i = 0; i < 8; ++i) acc[j][i] = b1v[i];

  // ---- k-chunk loop: one barrier per 16-k chunk ----
  #pragma unroll 1
  for (int kb = 0; kb < NCH; ++kb) {
    if (kb + 1 < NCH) {   // prefetch next fea chunk (64B contiguous)
      #pragma unroll
      for (int q = 0; q < 4; ++q)
        st[q] = *(const float4*)(frow + (kb + 1) * KCH + q * 4);
    }
    const float* sAc = &sA[kb & 1][0][0];
    #pragma unroll
    for (int k = 0; k < KCH; ++k) {
      const int kko = kb * KCH + k;
      float4 bA2, bB2;
      if (kko + 2 < C) {  // issue B(k+2): 2-deep pipeline (L2-hot)
        bA2 = *(const float4*)(wcol + (size_t)(kko + 2) * C);
        bB2 = *(const float4*)(wcol + (size_t)(kko + 2) * C + 4);
      }
      float4 a0 = *(const float4*)(sAc + k * SROWP + prow);
      float4 a1 = *(const float4*)(sAc + k * SROWP + prow + 4);
      float4 a2 = *(const float4*)(sAc + k * SROWP + prow + 8);
      float4 a3 = *(const float4*)(sAc + k * SROWP + prow + 12);
      float af[16] = {a0.x, a0.y, a0.z, a0.w, a1.x, a1.y, a1.z, a1.w,
                      a2.x, a2.y, a2.z, a2.w, a3.x, a3.y, a3.z, a3.w};
      float bf[8]  = {bAc.x, bAc.y, bAc.z, bAc.w, bBc.x, bBc.y, bBc.z, bBc.w};
      #pragma unroll
      for (int j = 0; j < 16; ++j)
        #pragma unroll
        for (int i = 0; i < 8; ++i)
          acc[j][i] = fmaf(af[j], bf[i], acc[j][i]);
      bAc = bAn; bBc = bBn;
      if (kko + 2 < C) { bAn = bA2; bBn = bB2; }
    }
    if (kb + 1 < NCH) {
      float* d = &sA[(kb + 1) & 1][0][ptid];
      #pragma unroll
      for (int q = 0; q < 4; ++q) {
        d[(q*4+0)*SROWP] = st[q].x; d[(q*4+1)*SROWP] = st[q].y;
        d[(q*4+2)*SROWP] = st[q].z; d[(q*4+3)*SROWP] = st[q].w;
      }
    }
    __syncthreads();
  }

  // ---- epilogue: relu + store h, f64 pred, segment max ----
  float w2f[8];
  #pragma unroll
  for (int i = 0; i < 8; ++i) w2f[i] = W2[coloff + i];
  double pdv[16];
  #pragma unroll
  for (int j = 0; j < 16; ++j) {
    float hv[8];
    #pragma unroll
    for (int i = 0; i < 8; ++i) hv[i] = fmaxf(acc[j][i], 0.f);
    const size_t row = trow + rowoff + j;
    *(float4*)(out + row * C + coloff)     = make_float4(hv[0], hv[1], hv[2], hv[3]);
    *(float4*)(out + row * C + coloff + 4) = make_float4(hv[4], hv[5], hv[6], hv[7]);
    double pd = 0.0;
    #pragma unroll
    for (int i = 0; i < 8; ++i) pd += (double)hv[i] * (double)w2f[i];
    pdv[j] = pd;
  }
  #pragma unroll
  for (int j = 0; j < 16; ++j) {   // reduce over the 8-lane col group
    double pd = pdv[j];
    pd += __shfl_xor(pd, 1, 64);
    pd += __shfl_xor(pd, 2, 64);
    pd += __shfl_xor(pd, 4, 64);
    pdv[j] = pd;
  }
  double* sPred = (double*)&sA[0][0][0];   // 512 doubles (4KB) overlay
  if ((lane & 7) == 0) {
    #pragma unroll
    for (int j = 0; j < 16; ++j) sPred[wc * TILE_R + rowoff + j] = pdv[j];
  }
  __syncthreads();
  {
    const size_t row = trow + tid;          // tid covers 0..255 == TILE_R
    const double s = sPred[tid] + sPred[TILE_R + tid] + b2d;
    const float pv = (float)s;
    pred[row] = pv;
    atomicMax(&segkey[vox[row]], f2key(pv));
  }
}

// ---------------------------------------------------------------------------
// Pass A: valkey + per-row histogram of byte1 (vk>>24), LDS-accumulated.
// ---------------------------------------------------------------------------
__global__ __launch_bounds__(256) void k_histA(
    const float* __restrict__ pred, const int* __restrict__ vox,
    const unsigned* __restrict__ segkey, unsigned* __restrict__ valkey,
    unsigned* __restrict__ histA, int N, int M)
{
  __shared__ unsigned lh[BATCH * 256];
  for (int b = threadIdx.x; b < BATCH * 256; b += 256) lh[b] = 0;
  __syncthreads();
  const int stride = gridDim.x * 256;
  for (int i = blockIdx.x * 256 + threadIdx.x; i < N; i += stride) {
    unsigned kk = f2key(pred[i]);
    unsigned vk = (kk == segkey[vox[i]]) ? 0xFFFFFFFFu : kk;
    valkey[i] = vk;
    atomicAdd(&lh[(i / M) * 256 + (vk >> 24)], 1u);
  }
  __syncthreads();
  for (int b = threadIdx.x; b < BATCH * 256; b += 256)
    if (lh[b]) atomicAdd(&histA[b], lh[b]);
}

// Pass B: byte2 among elements whose byte1 matches the selected bin.
__global__ __launch_bounds__(256) void k_histB(
    const unsigned* __restrict__ valkey, const unsigned* __restrict__ sel,
    unsigned* __restrict__ histB, int N, int M)
{
  __shared__ unsigned lh[BATCH * 256];
  for (int b = threadIdx.x; b < BATCH * 256; b += 256) lh[b] = 0;
  __syncthreads();
  const int stride = gridDim.x * 256;
  for (int i = blockIdx.x * 256 + threadIdx.x; i < N; i += stride) {
    unsigned vk = valkey[i];
    int row = i / M;
    if ((vk >> 24) == sel[row * 4 + 0])
      atomicAdd(&lh[row * 256 + ((vk >> 16) & 255u)], 1u);
  }
  __syncthreads();
  for (int b = threadIdx.x; b < BATCH * 256; b += 256)
    if (lh[b]) atomicAdd(&histB[b], lh[b]);
}

// Pass C: low 16 bits among elements whose top16 matches (few -> global ok).
__global__ __launch_bounds__(256) void k_histC(
    const unsigned* __restrict__ valkey, const unsigned* __restrict__ sel,
    unsigned* __restrict__ histC, int N, int M)
{
  const int stride = gridDim.x * 256;
  for (int i = blockIdx.x * 256 + threadIdx.x; i < N; i += stride) {
    unsigned vk = valkey[i];
    int row = i / M;
    if ((vk >> 16) == sel[row * 4 + 0])
      atomicAdd(&histC[(size_t)row * 65536 + (vk & 0xFFFFu)], 1u);
  }
}

// scans: find smallest bin with cumulative count >= k (k = M - target_num)
__global__ void k_scan256(const unsigned* __restrict__ hist,
                          unsigned* __restrict__ sel,
                          const int* __restrict__ tnum, int M, int pass)
{
  const int row = blockIdx.x;
  __shared__ unsigned h[256];
  h[threadIdx.x] = hist[row * 256 + threadIdx.x];
  __syncthreads();
  if (threadIdx.x == 0) {
    const unsigned k = (unsigned)(M - tnum[0]);
    unsigned cum = (pass == 0) ? 0u : sel[row * 4 + 1];
    unsigned bin = 255;
    for (int i = 0; i < 256; ++i) {
      if (cum + h[i] >= k) { bin = (unsigned)i; break; }
      cum += h[i];
    }
    if (pass == 0) { sel[row * 4 + 0] = bin; }
    else           { sel[row * 4 + 0] = (sel[row * 4 + 0] << 8) | bin; }
    sel[row * 4 + 1] = cum;
  }
}

__global__ void k_scan64k(const unsigned* __restrict__ hist,
                          unsigned* __restrict__ sel,
                          const int* __restrict__ tnum, int M)
{
  const int row = blockIdx.x;
  const int t = threadIdx.x;  // 256
  const unsigned* h = hist + (size_t)row * 65536;
  __shared__ unsigned part[256];
  const uint4* hv = (const uint4*)(h + t * 256);
  unsigned s = 0;
  for (int i = 0; i < 64; ++i) { uint4 v = hv[i]; s += v.x + v.y + v.z + v.w; }
  part[t] = s;
  __syncthreads();
  if (t == 0) {
    const unsigned k = (unsigned)(M - tnum[0]);
    unsigned cum = sel[row * 4 + 1];
    int seg = 255;
    for (int i = 0; i < 256; ++i) {
      if (cum + part[i] >= k) { seg = i; break; }
      cum += part[i];
    }
    unsigned bin = 0;
    for (int i = 0; i < 256; ++i) {
      unsigned c = h[seg * 256 + i];
      if (cum + c >= k) { bin = (unsigned)(seg * 256 + i); break; }
      cum += c;
    }
    sel[row * 4 + 2] = (sel[row * 4 + 0] << 16) | bin;
  }
}

__global__ void k_scatter(const int* __restrict__ tidx, float* __restrict__ kt, int n)
{
  int i = blockIdx.x * blockDim.x + threadIdx.x;
  if (i < n) kt[tidx[i]] = 1.0f;
}

// zero rows that are not kept.  keep = (valkey > thr) | is_target
__global__ __launch_bounds__(256) void k_final(const unsigned* __restrict__ valkey,
    const float* __restrict__ kt, const unsigned* __restrict__ sel,
    float* __restrict__ out, int N, int M)
{
  const int wid = threadIdx.x >> 6;
  const int lane = threadIdx.x & 63;
  const int nw = gridDim.x * 4;
  for (int r = blockIdx.x * 4 + wid; r < N; r += nw) {
    unsigned vk = valkey[r];
    float kv = kt[r];
    unsigned thr = sel[(r / M) * 4 + 2];
    bool keep = (vk > thr) || (kv != 0.0f);
    if (!keep)
      *(float2*)&out[(size_t)r * C + lane * 2] = make_float2(0.f, 0.f);
  }
}

// ---------------------------------------------------------------------------
extern "C" void kernel_launch(void* const* d_in, const int* in_sizes, int n_in,
                              void* d_out, int out_size, void* d_ws, size_t ws_size,
                              hipStream_t stream)
{
  const float* fea = (const float*)d_in[0];
  const float* W1  = (const float*)d_in[1];
  const float* b1  = (const float*)d_in[2];
  const float* W2  = (const float*)d_in[3];
  const float* b2  = (const float*)d_in[4];
  const int* vox   = (const int*)d_in[5];
  const int* tidx  = (const int*)d_in[6];
  const int* tnum  = (const int*)d_in[7];

  const int N = in_sizes[5];      // 800000
  const int M = N / BATCH;        // 100000
  const int nT = in_sizes[6];     // 400000
  const int nTiles = N / TILE_R;  // 3125 exact

  float* out  = (float*)d_out;
  float* pred = out + (size_t)N * C;
  float* kt   = pred + N;

  // workspace layout (zeroed region first, then valkey)
  char* w = (char*)d_ws;
  unsigned* segkey = (unsigned*)(w);                       // 512KB
  unsigned* histA  = (unsigned*)(w + (512u << 10));        // 8KB
  unsigned* histB  = (unsigned*)(w + (520u << 10));        // 8KB
  unsigned* sel    = (unsigned*)(w + (528u << 10));        // 4KB
  unsigned* histC  = (unsigned*)(w + (532u << 10));        // 2MB
  unsigned* valkey = (unsigned*)(w + (532u << 10) + (2u << 20));

  const size_t zbytes = (532u << 10) + (2u << 20);
  hipMemsetAsync(d_ws, 0, zbytes, stream);
  hipMemsetAsync(kt, 0, (size_t)N * sizeof(float), stream);

  k_scatter<<<(nT + 255) / 256, 256, 0, stream>>>(tidx, kt, nT);
  k_gemm<<<nTiles, TPB, 0, stream>>>(fea, W1, b1, W2, b2, vox,
                                     out, pred, segkey, N);
  k_histA<<<HGRID, 256, 0, stream>>>(pred, vox, segkey, valkey, histA, N, M);
  k_scan256<<<BATCH, 256, 0, stream>>>(histA, sel, tnum, M, 0);
  k_histB<<<HGRID, 256, 0, stream>>>(valkey, sel, histB, N, M);
  k_scan256<<<BATCH, 256, 0, stream>>>(histB, sel, tnum, M, 1);
  k_histC<<<HGRID, 256, 0, stream>>>(valkey, sel, histC, N, M);
  k_scan64k<<<BATCH, 256, 0, stream>>>(histC, sel, tnum, M);
  k_final<<<2048, 256, 0, stream>>>(valkey, kt, sel, out, N, M);
}

// Round 15
// 557.762 us; speedup vs baseline: 5.8298x; 1.9006x over previous
//
#include <hip/hip_runtime.h>
#include <stdint.h>

#define BATCH 8
#define C 128
#define TPB 256
#define GEMM_BLOCKS 512   // persistent, 2 blocks/CU (66KB LDS each)
#define TILE_R 128
#define HGRID 2048

// order-preserving float -> uint key (monotone: a<b  <=>  key(a)<key(b))
__device__ __forceinline__ unsigned f2key(float f){
  unsigned b = __float_as_uint(f);
  return (b & 0x80000000u) ? ~b : (b | 0x80000000u);
}

// ---------------------------------------------------------------------------
// Outer-product GEMM, 8x8/thread, 4-k-wide operand reads, ZERO main-loop
// barriers. Budget analysis of r9 (best, 444us): 682 cyc per k-step per CU =
// 256 VALU + 384 LDS-pipe (8 waves x 4 ds_read_b128/k) + latency/barriers.
// Fix the LDS term and the barriers, keep the proven 64-reg accumulator:
//  - B: W1 TRANSPOSED in LDS [c][k] (64KB, staged once per persistent block)
//    with XOR-granule swizzle (granule = (k>>2) ^ ((c>>3)&7)): the 8
//    col-lane-groups land on 8 distinct 16B bank positions -> conflict-free
//    b128 serving 4 k-steps => 2 LDS instr/k/wave (was 4).
//    Per CU: 8 waves x 2 x 12cyc = 192 < 256 VALU cyc/k.
//  - A: directly from global, NATURAL layout fea[row][k:k+4] (16B per
//    lane-group; 64B lines reused over 4 k-groups from L1; working set
//    2 blocks x 128 rows x 64B = 16KB/CU). No staging, no barriers.
// Registers: acc 64 + A ping/pong 64 + B 32 ~ 185 -> TPB=256 allocates
// freely (r12: 140; r14's balloon was a 128-reg acc body). 2 waves/SIMD.
// r13 lesson: TPB=512 is hard-capped at 128 VGPR - never again for this body.
// FMA chains (h and pred) operand/order-identical to rounds 1-14.
// ---------------------------------------------------------------------------
__global__ __launch_bounds__(TPB, 1) void k_gemm(
    const float* __restrict__ fea, const float* __restrict__ W1,
    const float* __restrict__ b1, const float* __restrict__ W2,
    const float* __restrict__ b2, const int* __restrict__ vox,
    float* __restrict__ out, float* __restrict__ pred,
    unsigned* __restrict__ segkey, int N)
{
  __shared__ float sW1t[C * C];        // 64KB: W1[k][c] at [c][swz(k)]
  __shared__ double sPredS[2 * TILE_R];// 2KB

  const int tid  = threadIdx.x;
  const int lane = tid & 63;
  const int wid  = tid >> 6;              // 0..3
  const int wr   = wid >> 1;              // 0..1 row-group
  const int wc   = wid & 1;               // 0..1 col-group
  const int rowoff = wr * 64 + (lane >> 3) * 8;   // 0..120
  const int coloff = wc * 64 + (lane & 7) * 8;    // 0..120
  const int lmask  = lane & 7;

  // ---- stage W1 transposed + granule-swizzled (once per block) ----
  for (int idx = tid; idx < C * C; idx += TPB) {
    int k = idx >> 7, c = idx & 127;     // coalesced read of W1[k][c]
    sW1t[c * C + (((k >> 2) ^ ((c >> 3) & 7)) << 2) + (k & 3)] = W1[idx];
  }
  float b1v[8];
  #pragma unroll
  for (int i = 0; i < 8; ++i) b1v[i] = b1[coloff + i];
  const double b2d = (double)b2[0];
  __syncthreads();

  const int nTiles = N / TILE_R;          // 6250 exact
  const float* bcol = &sW1t[coloff * C];  // B block base for this thread

  for (int tile = blockIdx.x; tile < nTiles; tile += GEMM_BLOCKS) {
    const size_t trow = (size_t)tile * TILE_R;
    const float* abase = fea + (trow + rowoff) * C;   // row j at + j*C

    float4 Aa[8], Ab[8];
    #pragma unroll
    for (int j = 0; j < 8; ++j) Aa[j] = *(const float4*)(abase + j * C);

    float acc[8][8];
    #pragma unroll
    for (int j = 0; j < 8; ++j)
      #pragma unroll
      for (int i = 0; i < 8; ++i) acc[j][i] = b1v[i];

    #pragma unroll 1
    for (int kg = 0; kg < 32; kg += 2) {
      // ---- half 1: compute group kg (Aa), prefetch kg+1 -> Ab ----
      #pragma unroll
      for (int j = 0; j < 8; ++j)
        Ab[j] = *(const float4*)(abase + j * C + (kg + 1) * 4);
      {
        const int goff = ((kg ^ lmask) << 2);
        float4 Bv[8];
        #pragma unroll
        for (int i = 0; i < 8; ++i)
          Bv[i] = *(const float4*)(bcol + i * C + goff);
        #pragma unroll
        for (int j = 0; j < 8; ++j) {   // kk ascending per (j,i) chain
          #pragma unroll
          for (int i = 0; i < 8; ++i) acc[j][i] = fmaf(Aa[j].x, Bv[i].x, acc[j][i]);
          #pragma unroll
          for (int i = 0; i < 8; ++i) acc[j][i] = fmaf(Aa[j].y, Bv[i].y, acc[j][i]);
          #pragma unroll
          for (int i = 0; i < 8; ++i) acc[j][i] = fmaf(Aa[j].z, Bv[i].z, acc[j][i]);
          #pragma unroll
          for (int i = 0; i < 8; ++i) acc[j][i] = fmaf(Aa[j].w, Bv[i].w, acc[j][i]);
        }
      }
      // ---- half 2: compute group kg+1 (Ab), prefetch kg+2 -> Aa ----
      if (kg + 2 < 32) {
        #pragma unroll
        for (int j = 0; j < 8; ++j)
          Aa[j] = *(const float4*)(abase + j * C + (kg + 2) * 4);
      }
      {
        const int goff = (((kg + 1) ^ lmask) << 2);
        float4 Bv[8];
        #pragma unroll
        for (int i = 0; i < 8; ++i)
          Bv[i] = *(const float4*)(bcol + i * C + goff);
        #pragma unroll
        for (int j = 0; j < 8; ++j) {
          #pragma unroll
          for (int i = 0; i < 8; ++i) acc[j][i] = fmaf(Ab[j].x, Bv[i].x, acc[j][i]);
          #pragma unroll
          for (int i = 0; i < 8; ++i) acc[j][i] = fmaf(Ab[j].y, Bv[i].y, acc[j][i]);
          #pragma unroll
          for (int i = 0; i < 8; ++i) acc[j][i] = fmaf(Ab[j].z, Bv[i].z, acc[j][i]);
          #pragma unroll
          for (int i = 0; i < 8; ++i) acc[j][i] = fmaf(Ab[j].w, Bv[i].w, acc[j][i]);
        }
      }
    }

    // ---- epilogue: relu + store h, f64 pred, segment max ----
    float w2f[8];
    #pragma unroll
    for (int i = 0; i < 8; ++i) w2f[i] = W2[coloff + i];
    double pdv[8];
    #pragma unroll
    for (int j = 0; j < 8; ++j) {
      float hv[8];
      #pragma unroll
      for (int i = 0; i < 8; ++i) hv[i] = fmaxf(acc[j][i], 0.f);
      const size_t row = trow + rowoff + j;
      *(float4*)(out + row * C + coloff)     = make_float4(hv[0], hv[1], hv[2], hv[3]);
      *(float4*)(out + row * C + coloff + 4) = make_float4(hv[4], hv[5], hv[6], hv[7]);
      double pd = 0.0;
      #pragma unroll
      for (int i = 0; i < 8; ++i) pd += (double)hv[i] * (double)w2f[i];
      pdv[j] = pd;
    }
    #pragma unroll
    for (int j = 0; j < 8; ++j) {   // reduce over the 8-lane col group
      double pd = pdv[j];
      pd += __shfl_xor(pd, 1, 64);
      pd += __shfl_xor(pd, 2, 64);
      pd += __shfl_xor(pd, 4, 64);
      pdv[j] = pd;
    }
    if ((lane & 7) == 0) {
      #pragma unroll
      for (int j = 0; j < 8; ++j) sPredS[wc * TILE_R + rowoff + j] = pdv[j];
    }
    __syncthreads();
    if (tid < TILE_R) {
      const double s = sPredS[tid] + sPredS[TILE_R + tid] + b2d;
      const float pv = (float)s;
      const size_t row = trow + tid;
      pred[row] = pv;
      atomicMax(&segkey[vox[row]], f2key(pv));
    }
    __syncthreads();   // sPredS consumed before next tile overwrites it
  }
}

// ---------------------------------------------------------------------------
// Pass A: valkey + per-row histogram of byte1 (vk>>24), LDS-accumulated.
// ---------------------------------------------------------------------------
__global__ __launch_bounds__(256) void k_histA(
    const float* __restrict__ pred, const int* __restrict__ vox,
    const unsigned* __restrict__ segkey, unsigned* __restrict__ valkey,
    unsigned* __restrict__ histA, int N, int M)
{
  __shared__ unsigned lh[BATCH * 256];
  for (int b = threadIdx.x; b < BATCH * 256; b += 256) lh[b] = 0;
  __syncthreads();
  const int stride = gridDim.x * 256;
  for (int i = blockIdx.x * 256 + threadIdx.x; i < N; i += stride) {
    unsigned kk = f2key(pred[i]);
    unsigned vk = (kk == segkey[vox[i]]) ? 0xFFFFFFFFu : kk;
    valkey[i] = vk;
    atomicAdd(&lh[(i / M) * 256 + (vk >> 24)], 1u);
  }
  __syncthreads();
  for (int b = threadIdx.x; b < BATCH * 256; b += 256)
    if (lh[b]) atomicAdd(&histA[b], lh[b]);
}

// Pass B: byte2 among elements whose byte1 matches the selected bin.
__global__ __launch_bounds__(256) void k_histB(
    const unsigned* __restrict__ valkey, const unsigned* __restrict__ sel,
    unsigned* __restrict__ histB, int N, int M)
{
  __shared__ unsigned lh[BATCH * 256];
  for (int b = threadIdx.x; b < BATCH * 256; b += 256) lh[b] = 0;
  __syncthreads();
  const int stride = gridDim.x * 256;
  for (int i = blockIdx.x * 256 + threadIdx.x; i < N; i += stride) {
    unsigned vk = valkey[i];
    int row = i / M;
    if ((vk >> 24) == sel[row * 4 + 0])
      atomicAdd(&lh[row * 256 + ((vk >> 16) & 255u)], 1u);
  }
  __syncthreads();
  for (int b = threadIdx.x; b < BATCH * 256; b += 256)
    if (lh[b]) atomicAdd(&histB[b], lh[b]);
}

// Pass C: low 16 bits among elements whose top16 matches (few -> global ok).
__global__ __launch_bounds__(256) void k_histC(
    const unsigned* __restrict__ valkey, const unsigned* __restrict__ sel,
    unsigned* __restrict__ histC, int N, int M)
{
  const int stride = gridDim.x * 256;
  for (int i = blockIdx.x * 256 + threadIdx.x; i < N; i += stride) {
    unsigned vk = valkey[i];
    int row = i / M;
    if ((vk >> 16) == sel[row * 4 + 0])
      atomicAdd(&histC[(size_t)row * 65536 + (vk & 0xFFFFu)], 1u);
  }
}

// scans: find smallest bin with cumulative count >= k (k = M - target_num)
__global__ void k_scan256(const unsigned* __restrict__ hist,
                          unsigned* __restrict__ sel,
                          const int* __restrict__ tnum, int M, int pass)
{
  const int row = blockIdx.x;
  __shared__ unsigned h[256];
  h[threadIdx.x] = hist[row * 256 + threadIdx.x];
  __syncthreads();
  if (threadIdx.x == 0) {
    const unsigned k = (unsigned)(M - tnum[0]);
    unsigned cum = (pass == 0) ? 0u : sel[row * 4 + 1];
    unsigned bin = 255;
    for (int i = 0; i < 256; ++i) {
      if (cum + h[i] >= k) { bin = (unsigned)i; break; }
      cum += h[i];
    }
    if (pass == 0) { sel[row * 4 + 0] = bin; }
    else           { sel[row * 4 + 0] = (sel[row * 4 + 0] << 8) | bin; }
    sel[row * 4 + 1] = cum;
  }
}

__global__ void k_scan64k(const unsigned* __restrict__ hist,
                          unsigned* __restrict__ sel,
                          const int* __restrict__ tnum, int M)
{
  const int row = blockIdx.x;
  const int t = threadIdx.x;  // 256
  const unsigned* h = hist + (size_t)row * 65536;
  __shared__ unsigned part[256];
  const uint4* hv = (const uint4*)(h + t * 256);
  unsigned s = 0;
  for (int i = 0; i < 64; ++i) { uint4 v = hv[i]; s += v.x + v.y + v.z + v.w; }
  part[t] = s;
  __syncthreads();
  if (t == 0) {
    const unsigned k = (unsigned)(M - tnum[0]);
    unsigned cum = sel[row * 4 + 1];
    int seg = 255;
    for (int i = 0; i < 256; ++i) {
      if (cum + part[i] >= k) { seg = i; break; }
      cum += part[i];
    }
    unsigned bin = 0;
    for (int i = 0; i < 256; ++i) {
      unsigned c = h[seg * 256 + i];
      if (cum + c >= k) { bin = (unsigned)(seg * 256 + i); break; }
      cum += c;
    }
    sel[row * 4 + 2] = (sel[row * 4 + 0] << 16) | bin;
  }
}

__global__ void k_scatter(const int* __restrict__ tidx, float* __restrict__ kt, int n)
{
  int i = blockIdx.x * blockDim.x + threadIdx.x;
  if (i < n) kt[tidx[i]] = 1.0f;
}

// zero rows that are not kept.  keep = (valkey > thr) | is_target
__global__ __launch_bounds__(256) void k_final(const unsigned* __restrict__ valkey,
    const float* __restrict__ kt, const unsigned* __restrict__ sel,
    float* __restrict__ out, int N, int M)
{
  const int wid = threadIdx.x >> 6;
  const int lane = threadIdx.x & 63;
  const int nw = gridDim.x * 4;
  for (int r = blockIdx.x * 4 + wid; r < N; r += nw) {
    unsigned vk = valkey[r];
    float kv = kt[r];
    unsigned thr = sel[(r / M) * 4 + 2];
    bool keep = (vk > thr) || (kv != 0.0f);
    if (!keep)
      *(float2*)&out[(size_t)r * C + lane * 2] = make_float2(0.f, 0.f);
  }
}

// ---------------------------------------------------------------------------
extern "C" void kernel_launch(void* const* d_in, const int* in_sizes, int n_in,
                              void* d_out, int out_size, void* d_ws, size_t ws_size,
                              hipStream_t stream)
{
  const float* fea = (const float*)d_in[0];
  const float* W1  = (const float*)d_in[1];
  const float* b1  = (const float*)d_in[2];
  const float* W2  = (const float*)d_in[3];
  const float* b2  = (const float*)d_in[4];
  const int* vox   = (const int*)d_in[5];
  const int* tidx  = (const int*)d_in[6];
  const int* tnum  = (const int*)d_in[7];

  const int N = in_sizes[5];      // 800000
  const int M = N / BATCH;        // 100000
  const int nT = in_sizes[6];     // 400000

  float* out  = (float*)d_out;
  float* pred = out + (size_t)N * C;
  float* kt   = pred + N;

  // workspace layout (zeroed region first, then valkey)
  char* w = (char*)d_ws;
  unsigned* segkey = (unsigned*)(w);                       // 512KB
  unsigned* histA  = (unsigned*)(w + (512u << 10));        // 8KB
  unsigned* histB  = (unsigned*)(w + (520u << 10));        // 8KB
  unsigned* sel    = (unsigned*)(w + (528u << 10));        // 4KB
  unsigned* histC  = (unsigned*)(w + (532u << 10));        // 2MB
  unsigned* valkey = (unsigned*)(w + (532u << 10) + (2u << 20));

  const size_t zbytes = (532u << 10) + (2u << 20);
  hipMemsetAsync(d_ws, 0, zbytes, stream);
  hipMemsetAsync(kt, 0, (size_t)N * sizeof(float), stream);

  k_scatter<<<(nT + 255) / 256, 256, 0, stream>>>(tidx, kt, nT);
  k_gemm<<<GEMM_BLOCKS, TPB, 0, stream>>>(fea, W1, b1, W2, b2, vox,
                                          out, pred, segkey, N);
  k_histA<<<HGRID, 256, 0, stream>>>(pred, vox, segkey, valkey, histA, N, M);
  k_scan256<<<BATCH, 256, 0, stream>>>(histA, sel, tnum, M, 0);
  k_histB<<<HGRID, 256, 0, stream>>>(valkey, sel, histB, N, M);
  k_scan256<<<BATCH, 256, 0, stream>>>(histB, sel, tnum, M, 1);
  k_histC<<<HGRID, 256, 0, stream>>>(valkey, sel, histC, N, M);
  k_scan64k<<<BATCH, 256, 0, stream>>>(histC, sel, tnum, M);
  k_final<<<2048, 256, 0, stream>>>(valkey, kt, sel, out, N, M);
}